// Round 3
// baseline (1565.825 us; speedup 1.0000x reference)
//
#include <hip/hip_runtime.h>

#define C_IN  32
#define C_OUT 64
#define KK    27
#define RB    128      // output rows per bucket
#define ASTR  65       // LDS accumulator row stride (bank-conflict break)

using frag_ab = __attribute__((ext_vector_type(8))) short;  // 8 bf16
using frag_cd = __attribute__((ext_vector_type(4))) float;  // 4 fp32

static __device__ inline unsigned short f2bf(float f) {   // RTNE f32->bf16
    unsigned u = __float_as_uint(f);
    return (unsigned short)((u + 0x7fffu + ((u >> 16) & 1u)) >> 16);
}

// ===========================================================================
// Fallback path (round-1, passing) if workspace too small
// ===========================================================================
__global__ __launch_bounds__(256) void sic_init_bias(float4* __restrict__ out4,
                                                     const float4* __restrict__ bias4,
                                                     int total4) {
    int idx = blockIdx.x * 256 + threadIdx.x, stride = gridDim.x * 256;
    for (int i = idx; i < total4; i += stride) out4[i] = bias4[i & 15];
}

__global__ __launch_bounds__(256) void sic_scatter(
    const float* __restrict__ feats, const float* __restrict__ weight,
    const int* __restrict__ bwd, const int* __restrict__ in_idx,
    const int* __restrict__ out_idx, float* __restrict__ out, int n_in)
{
    const int k = blockIdx.y, lane = threadIdx.x & 63, wid = threadIdx.x >> 6;
    float w[C_IN];
    const float* wk = weight + k * (C_IN * C_OUT);
#pragma unroll
    for (int i = 0; i < C_IN; ++i) w[i] = wk[i * C_OUT + lane];
    const int waves_total = gridDim.x * 4;
    const long long base = (long long)k * n_in;
    for (int p = blockIdx.x * 4 + wid; p < n_in; p += waves_total) {
        int src = __builtin_amdgcn_readfirstlane(in_idx[base + p]);
        int dst = __builtin_amdgcn_readfirstlane(out_idx[base + p]);
        int row = __builtin_amdgcn_readfirstlane(bwd[src]);
        const float* f = feats + (long long)row * C_IN;
        float acc = 0.0f;
#pragma unroll
        for (int i = 0; i < C_IN; ++i) acc = fmaf(f[i], w[i], acc);
        atomicAdd(out + (long long)dst * C_OUT + lane, acc);
    }
}

// ===========================================================================
// Prep kernels
// ===========================================================================
__global__ __launch_bounds__(512) void sic_zero(int* __restrict__ p, int n) {
    int i = blockIdx.x * 512 + threadIdx.x, stride = gridDim.x * 512;
    for (; i < n; i += stride) p[i] = 0;
}

// feats (f32) -> featsbf (bf16), plus one zeroed pad row at index n_in
__global__ __launch_bounds__(256) void sic_fconv(const float* __restrict__ feats,
                                                 short* __restrict__ featsbf, int n_in) {
    int t = blockIdx.x * 256 + threadIdx.x;
    if (t >= (n_in + 1) * 4) return;
    int row = t >> 2, c8 = (t & 3) * 8;
    uint4 v = {0u, 0u, 0u, 0u};
    if (row < n_in) {
        const float* fp = feats + (size_t)row * C_IN + c8;
        float4 f0 = ((const float4*)fp)[0];
        float4 f1 = ((const float4*)fp)[1];
        v.x = (unsigned)f2bf(f0.x) | ((unsigned)f2bf(f0.y) << 16);
        v.y = (unsigned)f2bf(f0.z) | ((unsigned)f2bf(f0.w) << 16);
        v.z = (unsigned)f2bf(f1.x) | ((unsigned)f2bf(f1.y) << 16);
        v.w = (unsigned)f2bf(f1.z) | ((unsigned)f2bf(f1.w) << 16);
    }
    ((uint4*)featsbf)[t] = v;
}

// weight (f32 [27][32][64]) -> wfrag bf16 B-fragments [27][4][64 lanes][8]
// lane l, k-chunk g=l>>4, col cl=l&15: elems W[k][g*8+j][nb*16+cl]
__global__ __launch_bounds__(256) void sic_wconv(const float* __restrict__ weight,
                                                 short* __restrict__ wfrag) {
    int t = blockIdx.x * 256 + threadIdx.x;
    if (t >= KK * 4 * 64) return;
    int l = t & 63, nb = (t >> 6) & 3, k = t >> 8;
    int g = l >> 4, cl = l & 15;
    const float* wp = weight + (size_t)k * (C_IN * C_OUT) + nb * 16 + cl;
    unsigned short r[8];
#pragma unroll
    for (int j = 0; j < 8; ++j) r[j] = f2bf(wp[(size_t)(g * 8 + j) * C_OUT]);
    uint4 v;
    v.x = (unsigned)r[0] | ((unsigned)r[1] << 16);
    v.y = (unsigned)r[2] | ((unsigned)r[3] << 16);
    v.z = (unsigned)r[4] | ((unsigned)r[5] << 16);
    v.w = (unsigned)r[6] | ((unsigned)r[7] << 16);
    ((uint4*)wfrag)[t] = v;
}

// histogram of (bucket, k) sub-lists
__global__ __launch_bounds__(256) void sic_hist(const int* __restrict__ out_idx,
                                                int* __restrict__ count, int n_in) {
    int k = blockIdx.y, p = blockIdx.x * 256 + threadIdx.x;
    if (p < n_in) {
        int dst = out_idx[(size_t)k * n_in + p];
        atomicAdd(&count[(dst >> 7) * KK + k], 1);
    }
}

__global__ __launch_bounds__(512) void sic_scan1(const int* __restrict__ count,
                                                 int* __restrict__ startv,
                                                 int* __restrict__ sums, int n) {
    __shared__ int sm[512];
    int tid = threadIdx.x, g = blockIdx.x * 512 + tid;
    int e = (g < n) ? count[g] : 0;
    sm[tid] = e;
    __syncthreads();
    for (int off = 1; off < 512; off <<= 1) {
        int t = (tid >= off) ? sm[tid - off] : 0;
        __syncthreads();
        sm[tid] += t;
        __syncthreads();
    }
    if (g < n) startv[g] = sm[tid] - e;
    if (tid == 511) sums[blockIdx.x] = sm[511];
}

__global__ __launch_bounds__(512) void sic_scan2(int* __restrict__ sums, int n) {
    __shared__ int sm[512];
    int tid = threadIdx.x;
    int e = (tid < n) ? sums[tid] : 0;
    sm[tid] = e;
    __syncthreads();
    for (int off = 1; off < 512; off <<= 1) {
        int t = (tid >= off) ? sm[tid - off] : 0;
        __syncthreads();
        sm[tid] += t;
        __syncthreads();
    }
    if (tid < n) sums[tid] = sm[tid] - e;
}

__global__ __launch_bounds__(512) void sic_scan3(int* __restrict__ startv,
                                                 int* __restrict__ cursor,
                                                 const int* __restrict__ sums, int n) {
    int g = blockIdx.x * 512 + threadIdx.x;
    if (g < n) {
        int v = startv[g] + sums[blockIdx.x];
        startv[g] = v;
        cursor[g] = v;
    }
}

// scatter packed records (src_row<<8 | dst_low7) into sub-bucket lists
__global__ __launch_bounds__(256) void sic_fill(const int* __restrict__ in_idx,
                                                const int* __restrict__ out_idx,
                                                const int* __restrict__ bwd,
                                                int* __restrict__ cursor,
                                                unsigned int* __restrict__ recs,
                                                int n_in) {
    int k = blockIdx.y, p = blockIdx.x * 256 + threadIdx.x;
    if (p < n_in) {
        size_t base = (size_t)k * n_in + p;
        int dst = out_idx[base];
        int src = in_idx[base];
        int row = bwd[src];
        int pos = atomicAdd(&cursor[(dst >> 7) * KK + k], 1);
        recs[pos] = ((unsigned)row << 8) | (unsigned)(dst & (RB - 1));
    }
}

// ===========================================================================
// MFMA accumulate: per bucket, tile 16 records x 64 channels per wave step
// ===========================================================================
__global__ __launch_bounds__(512) void sic_accum_mfma(
    const unsigned int* __restrict__ recs,
    const int* __restrict__ startv,
    const int* __restrict__ count,
    const short* __restrict__ featsbf,   // [(n_in+16)][32] bf16
    const short* __restrict__ wfrag,     // [27][4][64][8] bf16
    const float* __restrict__ bias,
    float* __restrict__ out,
    int zrow)
{
    __shared__ float acc[RB * ASTR];     // 33.3 KB, stride-65
    const int tid = threadIdx.x;
    for (int i = tid; i < RB * ASTR; i += 512) acc[i] = 0.0f;
    __syncthreads();

    const int wid = tid >> 6, lane = tid & 63;
    const int g = lane >> 4, cl = lane & 15;
    const int b = blockIdx.x;
    const frag_cd zf = {0.f, 0.f, 0.f, 0.f};

    for (int kk = wid; kk < KK; kk += 8) {
        // B-fragments for W[kk], 4 n-blocks, pinned in 16 VGPRs
        frag_ab bw0 = *(const frag_ab*)(wfrag + ((size_t)(kk * 4 + 0) * 64 + lane) * 8);
        frag_ab bw1 = *(const frag_ab*)(wfrag + ((size_t)(kk * 4 + 1) * 64 + lane) * 8);
        frag_ab bw2 = *(const frag_ab*)(wfrag + ((size_t)(kk * 4 + 2) * 64 + lane) * 8);
        frag_ab bw3 = *(const frag_ab*)(wfrag + ((size_t)(kk * 4 + 3) * 64 + lane) * 8);

        const int sb = b * KK + kk;
        const int s = __builtin_amdgcn_readfirstlane(startv[sb]);
        const int c = __builtin_amdgcn_readfirstlane(count[sb]);

        for (int t = 0; t < c; t += 16) {
            // lane-parallel record fetch: lane owns tile-row cl
            int idx = t + cl;
            unsigned rec = (unsigned)zrow << 8;       // tail mask -> zero feats row
            if (idx < c) rec = recs[s + idx];
            int row  = (int)(rec >> 8);
            int dstl = (idx < c) ? (int)(rec & (RB - 1)) : 0;

            // A-fragment: 16B vector load, fully lane-parallel
            frag_ab a = *(const frag_ab*)(featsbf + (size_t)row * C_IN + g * 8);

            frag_cd d0 = __builtin_amdgcn_mfma_f32_16x16x32_bf16(a, bw0, zf, 0, 0, 0);
            frag_cd d1 = __builtin_amdgcn_mfma_f32_16x16x32_bf16(a, bw1, zf, 0, 0, 0);
            frag_cd d2 = __builtin_amdgcn_mfma_f32_16x16x32_bf16(a, bw2, zf, 0, 0, 0);
            frag_cd d3 = __builtin_amdgcn_mfma_f32_16x16x32_bf16(a, bw3, zf, 0, 0, 0);

            // scatter: D reg j is pair-row g*4+j, channel nb*16+cl (m89 layout)
#pragma unroll
            for (int j = 0; j < 4; ++j) {
                int dl = __shfl(dstl, g * 4 + j, 64);
                float* ap = &acc[dl * ASTR + cl];
                atomicAdd(ap +  0, d0[j]);
                atomicAdd(ap + 16, d1[j]);
                atomicAdd(ap + 32, d2[j]);
                atomicAdd(ap + 48, d3[j]);
            }
        }
    }
    __syncthreads();

    // coalesced write-out with bias fused (each output written exactly once)
    const float4* bias4 = (const float4*)bias;
    float4* out4 = (float4*)out;
    for (int t = tid; t < RB * 16; t += 512) {
        int row = t >> 4, cq = t & 15;
        const float* ap = &acc[row * ASTR + cq * 4];
        float4 bb = bias4[cq];
        float4 v = {ap[0] + bb.x, ap[1] + bb.y, ap[2] + bb.z, ap[3] + bb.w};
        out4[(size_t)(b * RB + row) * 16 + cq] = v;
    }
}

// ===========================================================================
extern "C" void kernel_launch(void* const* d_in, const int* in_sizes, int n_in_cnt,
                              void* d_out, int out_size, void* d_ws, size_t ws_size,
                              hipStream_t stream) {
    const float* feats   = (const float*)d_in[0];
    const float* weight  = (const float*)d_in[1];
    const float* bias    = (const float*)d_in[2];
    const int*   bwd     = (const int*)d_in[3];
    const int*   in_idx  = (const int*)d_in[4];
    const int*   out_idx = (const int*)d_in[5];
    float*       out     = (float*)d_out;

    const int n_in  = in_sizes[0] / C_IN;      // 100000
    const int n_out = out_size / C_OUT;        // 800000
    const int NB    = (n_out + RB - 1) / RB;   // 6250
    const int NSB   = NB * KK;                 // 168750
    const int NCH   = (NSB + 511) / 512;       // 330
    const size_t P  = (size_t)KK * n_in;       // 2.7M

    // workspace layout (int units, 256-int aligned regions)
    const size_t NSBr   = ((size_t)NSB + 255) & ~(size_t)255;
    const size_t o_cnt  = 0;
    const size_t o_stv  = NSBr;
    const size_t o_cur  = 2 * NSBr;
    const size_t o_sum  = 3 * NSBr;
    const size_t o_rec  = o_sum + 512;
    const size_t o_fbf  = (o_rec + P + 255) & ~(size_t)255;
    const size_t fbf_i  = ((size_t)(n_in + 16) * C_IN * 2 + 3) / 4;   // shorts->ints
    const size_t o_wfr  = (o_fbf + fbf_i + 255) & ~(size_t)255;
    const size_t wfr_i  = (size_t)KK * 4 * 64 * 8 * 2 / 4;
    const size_t need   = (o_wfr + wfr_i) * sizeof(int);

    if (ws_size < need || NCH > 512) {
        const int total4 = out_size / 4;
        hipLaunchKernelGGL(sic_init_bias, dim3(2048), dim3(256), 0, stream,
                           (float4*)out, (const float4*)bias, total4);
        hipLaunchKernelGGL(sic_scatter, dim3(160, KK), dim3(256), 0, stream,
                           feats, weight, bwd, in_idx, out_idx, out, n_in);
        return;
    }

    int* ws = (int*)d_ws;
    int* count  = ws + o_cnt;
    int* startv = ws + o_stv;
    int* cursor = ws + o_cur;
    int* sums   = ws + o_sum;
    unsigned int* recs = (unsigned int*)(ws + o_rec);
    short* featsbf = (short*)(ws + o_fbf);
    short* wfrag   = (short*)(ws + o_wfr);

    dim3 gpair((n_in + 255) / 256, KK);

    hipLaunchKernelGGL(sic_zero,  dim3(330), dim3(512), 0, stream, count, NSB);
    hipLaunchKernelGGL(sic_fconv, dim3(((n_in + 1) * 4 + 255) / 256), dim3(256), 0, stream,
                       feats, featsbf, n_in);
    hipLaunchKernelGGL(sic_wconv, dim3((KK * 4 * 64 + 255) / 256), dim3(256), 0, stream,
                       weight, wfrag);
    hipLaunchKernelGGL(sic_hist,  gpair, dim3(256), 0, stream, out_idx, count, n_in);
    hipLaunchKernelGGL(sic_scan1, dim3(NCH), dim3(512), 0, stream, count, startv, sums, NSB);
    hipLaunchKernelGGL(sic_scan2, dim3(1),   dim3(512), 0, stream, sums, NCH);
    hipLaunchKernelGGL(sic_scan3, dim3(NCH), dim3(512), 0, stream, startv, cursor, sums, NSB);
    hipLaunchKernelGGL(sic_fill,  gpair, dim3(256), 0, stream,
                       in_idx, out_idx, bwd, cursor, recs, n_in);
    hipLaunchKernelGGL(sic_accum_mfma, dim3(NB), dim3(512), 0, stream,
                       recs, startv, count, featsbf, wfrag, bias, out, n_in);
}

// Round 5
// 712.059 us; speedup vs baseline: 2.1990x; 2.1990x over previous
//
#include <hip/hip_runtime.h>

#define C_IN  32
#define C_OUT 64
#define KK    27

using frag_ab = __attribute__((ext_vector_type(8))) short;  // 8 bf16
using frag_cd = __attribute__((ext_vector_type(4))) float;  // 4 fp32

static __device__ inline unsigned short f2bf(float f) {   // RTNE f32->bf16
    unsigned u = __float_as_uint(f);
    return (unsigned short)((u + 0x7fffu + ((u >> 16) & 1u)) >> 16);
}
static __device__ inline unsigned pack2(float a, float b) {
    return (unsigned)f2bf(a) | ((unsigned)f2bf(b) << 16);
}

// ===========================================================================
// Fallback path (round-1, passing, atomic-bound 660us) if workspace too small
// ===========================================================================
__global__ __launch_bounds__(256) void sic_init_bias(float4* __restrict__ out4,
                                                     const float4* __restrict__ bias4,
                                                     int total4) {
    int idx = blockIdx.x * 256 + threadIdx.x, stride = gridDim.x * 256;
    for (int i = idx; i < total4; i += stride) out4[i] = bias4[i & 15];
}

__global__ __launch_bounds__(256) void sic_scatter(
    const float* __restrict__ feats, const float* __restrict__ weight,
    const int* __restrict__ bwd, const int* __restrict__ in_idx,
    const int* __restrict__ out_idx, float* __restrict__ out, int n_in)
{
    const int k = blockIdx.y, lane = threadIdx.x & 63, wid = threadIdx.x >> 6;
    float w[C_IN];
    const float* wk = weight + k * (C_IN * C_OUT);
#pragma unroll
    for (int i = 0; i < C_IN; ++i) w[i] = wk[i * C_OUT + lane];
    const int waves_total = gridDim.x * 4;
    const long long base = (long long)k * n_in;
    for (int p = blockIdx.x * 4 + wid; p < n_in; p += waves_total) {
        int src = __builtin_amdgcn_readfirstlane(in_idx[base + p]);
        int dst = __builtin_amdgcn_readfirstlane(out_idx[base + p]);
        int row = __builtin_amdgcn_readfirstlane(bwd[src]);
        const float* f = feats + (long long)row * C_IN;
        float acc = 0.0f;
#pragma unroll
        for (int i = 0; i < C_IN; ++i) acc = fmaf(f[i], w[i], acc);
        atomicAdd(out + (long long)dst * C_OUT + lane, acc);
    }
}

// ===========================================================================
// Prep kernels
// ===========================================================================
__global__ __launch_bounds__(512) void sic_zero(int* __restrict__ p, int n) {
    int i = blockIdx.x * 512 + threadIdx.x, stride = gridDim.x * 512;
    for (; i < n; i += stride) p[i] = 0;
}

// feats (f32) -> featsbf (bf16), plus one zeroed pad row at index n_in
__global__ __launch_bounds__(256) void sic_fconv(const float* __restrict__ feats,
                                                 short* __restrict__ featsbf, int n_in) {
    int t = blockIdx.x * 256 + threadIdx.x;
    if (t >= (n_in + 1) * 4) return;
    int row = t >> 2, c8 = (t & 3) * 8;
    uint4 v = {0u, 0u, 0u, 0u};
    if (row < n_in) {
        const float* fp = feats + (size_t)row * C_IN + c8;
        float4 f0 = ((const float4*)fp)[0];
        float4 f1 = ((const float4*)fp)[1];
        v.x = pack2(f0.x, f0.y);
        v.y = pack2(f0.z, f0.w);
        v.z = pack2(f1.x, f1.y);
        v.w = pack2(f1.z, f1.w);
    }
    ((uint4*)featsbf)[t] = v;
}

// weight (f32 [27][32][64]) -> bf16 fragments [27][4][64 lanes][8]
// lane l (g=l>>4, cl=l&15), block nb: elems W[k][g*8+j][nb*16+cl]
// (used as the MFMA *A* operand: A[i=ch_sub][m=cin] = W[k][m][nb*16+i])
__global__ __launch_bounds__(256) void sic_wconv(const float* __restrict__ weight,
                                                 short* __restrict__ wfrag) {
    int t = blockIdx.x * 256 + threadIdx.x;
    if (t >= KK * 4 * 64) return;
    int l = t & 63, nb = (t >> 6) & 3, k = t >> 8;
    int g = l >> 4, cl = l & 15;
    const float* wp = weight + (size_t)k * (C_IN * C_OUT) + nb * 16 + cl;
    float r[8];
#pragma unroll
    for (int j = 0; j < 8; ++j) r[j] = wp[(size_t)(g * 8 + j) * C_OUT];
    uint4 v = {pack2(r[0], r[1]), pack2(r[2], r[3]), pack2(r[4], r[5]), pack2(r[6], r[7])};
    ((uint4*)wfrag)[t] = v;
}

// histogram by destination row (segment of the rulebook)
__global__ __launch_bounds__(256) void sic_hist2(const int* __restrict__ out_idx_seg,
                                                 int* __restrict__ count, int pseg) {
    int i = blockIdx.x * 256 + threadIdx.x;
    if (i < pseg) atomicAdd(&count[out_idx_seg[i]], 1);
}

// ---- 2-level exclusive scan machinery ----
__global__ __launch_bounds__(512) void sic_scan_chunk(const int* __restrict__ in,
                                                      int* __restrict__ outExcl,
                                                      int* __restrict__ sums, int n) {
    __shared__ int sm[512];
    int tid = threadIdx.x, g = blockIdx.x * 512 + tid;
    int e = (g < n) ? in[g] : 0;
    sm[tid] = e;
    __syncthreads();
    for (int off = 1; off < 512; off <<= 1) {
        int t = (tid >= off) ? sm[tid - off] : 0;
        __syncthreads();
        sm[tid] += t;
        __syncthreads();
    }
    if (g < n) outExcl[g] = sm[tid] - e;
    if (tid == 511) sums[blockIdx.x] = sm[511];
}

__global__ __launch_bounds__(512) void sic_scan_small(int* __restrict__ buf, int n) {
    __shared__ int sm[512];
    int tid = threadIdx.x;
    int e = (tid < n) ? buf[tid] : 0;
    sm[tid] = e;
    __syncthreads();
    for (int off = 1; off < 512; off <<= 1) {
        int t = (tid >= off) ? sm[tid - off] : 0;
        __syncthreads();
        sm[tid] += t;
        __syncthreads();
    }
    if (tid < n) buf[tid] = sm[tid] - e;
}

__global__ __launch_bounds__(512) void sic_scan_addback(int* __restrict__ arr,
                                                        const int* __restrict__ sums, int n) {
    int g = blockIdx.x * 512 + threadIdx.x;
    if (g < n) arr[g] += sums[blockIdx.x];
}

__global__ __launch_bounds__(512) void sic_scan_addback_cur(int* __restrict__ startv,
                                                            int* __restrict__ cursor,
                                                            const int* __restrict__ sums, int n) {
    int g = blockIdx.x * 512 + threadIdx.x;
    if (g < n) {
        int v = startv[g] + sums[blockIdx.x];
        startv[g] = v;
        cursor[g] = v;
    }
}

// assign each record its dst-sorted slot
__global__ __launch_bounds__(256) void sic_fill2(const int* __restrict__ out_idx_seg,
                                                 int* __restrict__ cursor,
                                                 int* __restrict__ posarr, int pseg) {
    int i = blockIdx.x * 256 + threadIdx.x;
    if (i < pseg) {
        int dst = out_idx_seg[i];
        posarr[i] = atomicAdd(&cursor[dst], 1);
    }
}

// ===========================================================================
// Phase A: per-k MFMA, flipped operands -> lane owns 4 consecutive channels
// of its own record; direct scattered bf16 stores to contrib[pos].
// ===========================================================================
__global__ __launch_bounds__(256) void sic_gemm(
    const int* __restrict__ in_idx,     // global rulebook [KK][n_in]
    const int* __restrict__ bwd,
    const int* __restrict__ posarr,     // segment-local [kseg][n_in]
    const short* __restrict__ featsbf,  // [(n_in+pad)][32] bf16
    const short* __restrict__ wfrag,    // [KK][4][64][8] bf16
    unsigned short* __restrict__ contrib,
    int n_in, int k0, int zrow)
{
    const int kk   = k0 + blockIdx.y;
    const int lane = threadIdx.x & 63;
    const int wid  = threadIdx.x >> 6;
    const int g = lane >> 4, cl = lane & 15;

    const frag_ab wa0 = *(const frag_ab*)(wfrag + ((size_t)(kk * 4 + 0) * 64 + lane) * 8);
    const frag_ab wa1 = *(const frag_ab*)(wfrag + ((size_t)(kk * 4 + 1) * 64 + lane) * 8);
    const frag_ab wa2 = *(const frag_ab*)(wfrag + ((size_t)(kk * 4 + 2) * 64 + lane) * 8);
    const frag_ab wa3 = *(const frag_ab*)(wfrag + ((size_t)(kk * 4 + 3) * 64 + lane) * 8);
    const frag_cd zf = {0.f, 0.f, 0.f, 0.f};

    const size_t gk = (size_t)kk * n_in;          // rulebook base
    const size_t sk = (size_t)blockIdx.y * n_in;  // segment posarr base
    const int ntiles = (n_in + 15) >> 4;
    const int wstep  = gridDim.x * 4;

    for (int t = blockIdx.x * 4 + wid; t < ntiles; t += wstep) {
        int idx = t * 16 + cl;                    // record owned by this cl
        bool valid = idx < n_in;
        int row = zrow, pos = 0;
        if (valid) {
            row = bwd[in_idx[gk + idx]];          // fused feats[bwd] gather
            pos = posarr[sk + idx];
        }
        // B-operand: feats row (16B vector load, lane-parallel)
        frag_ab b = *(const frag_ab*)(featsbf + (size_t)row * C_IN + g * 8);
        // D'[ch_sub][rec]: lane(g,cl) reg j = channel nb*16+g*4+j of record cl
        frag_cd d0 = __builtin_amdgcn_mfma_f32_16x16x32_bf16(wa0, b, zf, 0, 0, 0);
        frag_cd d1 = __builtin_amdgcn_mfma_f32_16x16x32_bf16(wa1, b, zf, 0, 0, 0);
        frag_cd d2 = __builtin_amdgcn_mfma_f32_16x16x32_bf16(wa2, b, zf, 0, 0, 0);
        frag_cd d3 = __builtin_amdgcn_mfma_f32_16x16x32_bf16(wa3, b, zf, 0, 0, 0);
        if (valid) {
            unsigned short* cp = contrib + (size_t)pos * C_OUT + g * 4;
            uint2 v0 = {pack2(d0[0], d0[1]), pack2(d0[2], d0[3])};
            uint2 v1 = {pack2(d1[0], d1[1]), pack2(d1[2], d1[3])};
            uint2 v2 = {pack2(d2[0], d2[1]), pack2(d2[2], d2[3])};
            uint2 v3 = {pack2(d3[0], d3[1]), pack2(d3[2], d3[3])};
            *(uint2*)(cp +  0) = v0;   // channels nb*16 + g*4 .. +3
            *(uint2*)(cp + 16) = v1;
            *(uint2*)(cp + 32) = v2;
            *(uint2*)(cp + 48) = v3;
        }
    }
}

// ===========================================================================
// Phase B: one wave per output row; contiguous streaming sum of contrib rows
// ===========================================================================
__global__ __launch_bounds__(256) void sic_reduce(
    const unsigned short* __restrict__ contrib,
    const int* __restrict__ startv, const int* __restrict__ count,
    const float* __restrict__ bias, float* __restrict__ out,
    int n_out, int first)
{
    int dst  = (blockIdx.x * 256 + threadIdx.x) >> 6;
    int lane = threadIdx.x & 63;
    if (dst >= n_out) return;
    int s = __builtin_amdgcn_readfirstlane(startv[dst]);
    int c = __builtin_amdgcn_readfirstlane(count[dst]);
    size_t obase = (size_t)dst * C_OUT + lane;
    float acc = first ? bias[lane] : out[obase];
    const unsigned short* cp = contrib + (size_t)s * C_OUT + lane;
    for (int j = 0; j < c; ++j)
        acc += __uint_as_float((unsigned)cp[(size_t)j * C_OUT] << 16);
    out[obase] = acc;
}

// ===========================================================================
extern "C" void kernel_launch(void* const* d_in, const int* in_sizes, int n_in_cnt,
                              void* d_out, int out_size, void* d_ws, size_t ws_size,
                              hipStream_t stream) {
    const float* feats   = (const float*)d_in[0];
    const float* weight  = (const float*)d_in[1];
    const float* bias    = (const float*)d_in[2];
    const int*   bwd     = (const int*)d_in[3];
    const int*   in_idx  = (const int*)d_in[4];
    const int*   out_idx = (const int*)d_in[5];
    float*       out     = (float*)d_out;

    const int n_in  = in_sizes[0] / C_IN;      // 100000
    const int n_out = out_size / C_OUT;        // 800000
    const size_t P  = (size_t)KK * n_in;       // 2.7M records

    const int NCH1 = (n_out + 511) / 512;      // 1563
    const int NCH2 = (NCH1 + 511) / 512;       // 4

    // ---- workspace layout (int units) ----
    const size_t NOUTr   = ((size_t)n_out + 255) & ~(size_t)255;
    const size_t o_cnt   = 0;
    const size_t o_stv   = NOUTr;
    const size_t o_cur   = 2 * NOUTr;
    const size_t o_s1    = 3 * NOUTr;                 // sums1 (NCH1)
    const size_t S1r     = ((size_t)NCH1 + 255) & ~(size_t)255;
    const size_t o_s1e   = o_s1 + S1r;                // sums1e (NCH1)
    const size_t o_s2    = o_s1e + S1r;               // sums2 (512)
    const size_t o_pos   = o_s2 + 512;                // posarr (P)
    const size_t o_fbf   = (o_pos + P + 255) & ~(size_t)255;
    const size_t fbf_i   = ((size_t)(n_in + 16) * C_IN * 2 + 3) / 4;
    const size_t o_wfr   = (o_fbf + fbf_i + 255) & ~(size_t)255;
    const size_t wfr_i   = (size_t)KK * 4 * 64 * 8 * 2 / 4;
    const size_t o_ctr   = (o_wfr + wfr_i + 255) & ~(size_t)255;  // contrib starts here

    const size_t ws_ints = ws_size / 4;
    // records that fit in the remaining workspace (64 shorts = 32 ints each)
    size_t cap_recs = (ws_ints > o_ctr) ? (ws_ints - o_ctr) / 32 : 0;
    int kseg_max = (int)(cap_recs / (size_t)n_in);
    if (kseg_max > KK) kseg_max = KK;

    if (kseg_max < 1 || NCH1 > 512 * 512 || NCH2 > 512 || NCH1 > (int)S1r) {
        // fallback: round-1 atomic path
        const int total4 = out_size / 4;
        hipLaunchKernelGGL(sic_init_bias, dim3(2048), dim3(256), 0, stream,
                           (float4*)out, (const float4*)bias, total4);
        hipLaunchKernelGGL(sic_scatter, dim3(160, KK), dim3(256), 0, stream,
                           feats, weight, bwd, in_idx, out_idx, out, n_in);
        return;
    }

    int* ws = (int*)d_ws;
    int* count  = ws + o_cnt;
    int* startv = ws + o_stv;
    int* cursor = ws + o_cur;
    int* sums1  = ws + o_s1;
    int* sums1e = ws + o_s1e;
    int* sums2  = ws + o_s2;
    int* posarr = ws + o_pos;
    short* featsbf = (short*)(ws + o_fbf);
    short* wfrag   = (short*)(ws + o_wfr);
    unsigned short* contrib = (unsigned short*)(ws + o_ctr);

    // one-time conversions
    hipLaunchKernelGGL(sic_fconv, dim3(((n_in + 1) * 4 + 255) / 256), dim3(256), 0, stream,
                       feats, featsbf, n_in);
    hipLaunchKernelGGL(sic_wconv, dim3((KK * 4 * 64 + 255) / 256), dim3(256), 0, stream,
                       weight, wfrag);

    // segment loop over k (single pass when contrib fits: kseg_max == 27)
    for (int k0 = 0; k0 < KK; k0 += kseg_max) {
        const int kseg = (KK - k0 < kseg_max) ? (KK - k0) : kseg_max;
        const int pseg = kseg * n_in;
        const int gp   = (pseg + 255) / 256;
        const int* oseg = out_idx + (size_t)k0 * n_in;

        hipLaunchKernelGGL(sic_zero, dim3(1024), dim3(512), 0, stream, count, n_out);
        hipLaunchKernelGGL(sic_hist2, dim3(gp), dim3(256), 0, stream, oseg, count, pseg);
        hipLaunchKernelGGL(sic_scan_chunk, dim3(NCH1), dim3(512), 0, stream,
                           count, startv, sums1, n_out);
        hipLaunchKernelGGL(sic_scan_chunk, dim3(NCH2), dim3(512), 0, stream,
                           sums1, sums1e, sums2, NCH1);
        hipLaunchKernelGGL(sic_scan_small, dim3(1), dim3(512), 0, stream, sums2, NCH2);
        hipLaunchKernelGGL(sic_scan_addback, dim3(NCH2), dim3(512), 0, stream,
                           sums1e, sums2, NCH1);
        hipLaunchKernelGGL(sic_scan_addback_cur, dim3(NCH1), dim3(512), 0, stream,
                           startv, cursor, sums1e, n_out);
        hipLaunchKernelGGL(sic_fill2, dim3(gp), dim3(256), 0, stream,
                           oseg, cursor, posarr, pseg);
        hipLaunchKernelGGL(sic_gemm, dim3(196, kseg), dim3(256), 0, stream,
                           in_idx, bwd, posarr, featsbf, wfrag, contrib,
                           n_in, k0, n_in);
        // one WAVE per output row: n_out*64 threads total
        hipLaunchKernelGGL(sic_reduce, dim3((n_out + 3) / 4), dim3(256), 0, stream,
                           contrib, startv, count, bias, out, n_out, (k0 == 0) ? 1 : 0);
    }
}

// Round 6
// 691.036 us; speedup vs baseline: 2.2659x; 1.0304x over previous
//
#include <hip/hip_runtime.h>

#define C_IN  32
#define C_OUT 64
#define KK    27

using frag_ab = __attribute__((ext_vector_type(8))) short;  // 8 bf16
using frag_cd = __attribute__((ext_vector_type(4))) float;  // 4 fp32

static __device__ inline unsigned short f2bf(float f) {   // RTNE f32->bf16
    unsigned u = __float_as_uint(f);
    return (unsigned short)((u + 0x7fffu + ((u >> 16) & 1u)) >> 16);
}
static __device__ inline unsigned pack2(float a, float b) {
    return (unsigned)f2bf(a) | ((unsigned)f2bf(b) << 16);
}
static __device__ inline float bflo(unsigned u) { return __uint_as_float(u << 16); }
static __device__ inline float bfhi(unsigned u) { return __uint_as_float(u & 0xffff0000u); }

// ===========================================================================
// Fallback path (round-1, passing, atomic-bound 660us) if workspace too small
// ===========================================================================
__global__ __launch_bounds__(256) void sic_init_bias(float4* __restrict__ out4,
                                                     const float4* __restrict__ bias4,
                                                     int total4) {
    int idx = blockIdx.x * 256 + threadIdx.x, stride = gridDim.x * 256;
    for (int i = idx; i < total4; i += stride) out4[i] = bias4[i & 15];
}

__global__ __launch_bounds__(256) void sic_scatter(
    const float* __restrict__ feats, const float* __restrict__ weight,
    const int* __restrict__ bwd, const int* __restrict__ in_idx,
    const int* __restrict__ out_idx, float* __restrict__ out, int n_in)
{
    const int k = blockIdx.y, lane = threadIdx.x & 63, wid = threadIdx.x >> 6;
    float w[C_IN];
    const float* wk = weight + k * (C_IN * C_OUT);
#pragma unroll
    for (int i = 0; i < C_IN; ++i) w[i] = wk[i * C_OUT + lane];
    const int waves_total = gridDim.x * 4;
    const long long base = (long long)k * n_in;
    for (int p = blockIdx.x * 4 + wid; p < n_in; p += waves_total) {
        int src = __builtin_amdgcn_readfirstlane(in_idx[base + p]);
        int dst = __builtin_amdgcn_readfirstlane(out_idx[base + p]);
        int row = __builtin_amdgcn_readfirstlane(bwd[src]);
        const float* f = feats + (long long)row * C_IN;
        float acc = 0.0f;
#pragma unroll
        for (int i = 0; i < C_IN; ++i) acc = fmaf(f[i], w[i], acc);
        atomicAdd(out + (long long)dst * C_OUT + lane, acc);
    }
}

// ===========================================================================
// Prep kernels
// ===========================================================================
__global__ __launch_bounds__(512) void sic_zero(int* __restrict__ p, int n) {
    int i = blockIdx.x * 512 + threadIdx.x, stride = gridDim.x * 512;
    for (; i < n; i += stride) p[i] = 0;
}

// feats (f32) -> featsbf (bf16), plus one zeroed pad row at index n_in
__global__ __launch_bounds__(256) void sic_fconv(const float* __restrict__ feats,
                                                 short* __restrict__ featsbf, int n_in) {
    int t = blockIdx.x * 256 + threadIdx.x;
    if (t >= (n_in + 1) * 4) return;
    int row = t >> 2, c8 = (t & 3) * 8;
    uint4 v = {0u, 0u, 0u, 0u};
    if (row < n_in) {
        const float* fp = feats + (size_t)row * C_IN + c8;
        float4 f0 = ((const float4*)fp)[0];
        float4 f1 = ((const float4*)fp)[1];
        v.x = pack2(f0.x, f0.y);
        v.y = pack2(f0.z, f0.w);
        v.z = pack2(f1.x, f1.y);
        v.w = pack2(f1.z, f1.w);
    }
    ((uint4*)featsbf)[t] = v;
}

// weight (f32 [27][32][64]) -> bf16 fragments [27][4][64 lanes][8]
// lane l (g=l>>4, cl=l&15), block nb: elems W[k][g*8+j][nb*16+cl]
// (used as the MFMA *A* operand: A[i=ch_sub][m=cin] = W[k][m][nb*16+i])
__global__ __launch_bounds__(256) void sic_wconv(const float* __restrict__ weight,
                                                 short* __restrict__ wfrag) {
    int t = blockIdx.x * 256 + threadIdx.x;
    if (t >= KK * 4 * 64) return;
    int l = t & 63, nb = (t >> 6) & 3, k = t >> 8;
    int g = l >> 4, cl = l & 15;
    const float* wp = weight + (size_t)k * (C_IN * C_OUT) + nb * 16 + cl;
    float r[8];
#pragma unroll
    for (int j = 0; j < 8; ++j) r[j] = wp[(size_t)(g * 8 + j) * C_OUT];
    uint4 v = {pack2(r[0], r[1]), pack2(r[2], r[3]), pack2(r[4], r[5]), pack2(r[6], r[7])};
    ((uint4*)wfrag)[t] = v;
}

// histogram by destination row (segment of the rulebook)
__global__ __launch_bounds__(256) void sic_hist2(const int* __restrict__ out_idx_seg,
                                                 int* __restrict__ count, int pseg) {
    int i = blockIdx.x * 256 + threadIdx.x;
    if (i < pseg) atomicAdd(&count[out_idx_seg[i]], 1);
}

// ---- 2-level exclusive scan machinery ----
__global__ __launch_bounds__(512) void sic_scan_chunk(const int* __restrict__ in,
                                                      int* __restrict__ outExcl,
                                                      int* __restrict__ sums, int n) {
    __shared__ int sm[512];
    int tid = threadIdx.x, g = blockIdx.x * 512 + tid;
    int e = (g < n) ? in[g] : 0;
    sm[tid] = e;
    __syncthreads();
    for (int off = 1; off < 512; off <<= 1) {
        int t = (tid >= off) ? sm[tid - off] : 0;
        __syncthreads();
        sm[tid] += t;
        __syncthreads();
    }
    if (g < n) outExcl[g] = sm[tid] - e;
    if (tid == 511) sums[blockIdx.x] = sm[511];
}

__global__ __launch_bounds__(512) void sic_scan_small(int* __restrict__ buf, int n) {
    __shared__ int sm[512];
    int tid = threadIdx.x;
    int e = (tid < n) ? buf[tid] : 0;
    sm[tid] = e;
    __syncthreads();
    for (int off = 1; off < 512; off <<= 1) {
        int t = (tid >= off) ? sm[tid - off] : 0;
        __syncthreads();
        sm[tid] += t;
        __syncthreads();
    }
    if (tid < n) buf[tid] = sm[tid] - e;
}

__global__ __launch_bounds__(512) void sic_scan_addback(int* __restrict__ arr,
                                                        const int* __restrict__ sums, int n) {
    int g = blockIdx.x * 512 + threadIdx.x;
    if (g < n) arr[g] += sums[blockIdx.x];
}

__global__ __launch_bounds__(512) void sic_scan_addback_cur(int* __restrict__ startv,
                                                            int* __restrict__ cursor,
                                                            const int* __restrict__ sums, int n) {
    int g = blockIdx.x * 512 + threadIdx.x;
    if (g < n) {
        int v = startv[g] + sums[blockIdx.x];
        startv[g] = v;
        cursor[g] = v;
    }
}

// inverse map: dst-sorted slot -> segment-local record id
__global__ __launch_bounds__(256) void sic_fill2(const int* __restrict__ out_idx_seg,
                                                 int* __restrict__ cursor,
                                                 int* __restrict__ ridx, int pseg) {
    int i = blockIdx.x * 256 + threadIdx.x;
    if (i < pseg) {
        int dst = out_idx_seg[i];
        int pos = atomicAdd(&cursor[dst], 1);
        ridx[pos] = i;
    }
}

// ===========================================================================
// Phase A: per-k MFMA; contrib written in RECORD ORDER (fully coalesced).
// Lane (g,cl) reg j of D = channel nb*16+g*4+j of record cl (round-5 verified).
// ===========================================================================
__global__ __launch_bounds__(256) void sic_gemm(
    const int* __restrict__ in_idx,     // global rulebook [KK][n_in]
    const int* __restrict__ bwd,
    const short* __restrict__ featsbf,  // [(n_in+pad)][32] bf16
    const short* __restrict__ wfrag,    // [KK][4][64][8] bf16
    unsigned short* __restrict__ contrib,
    int n_in, int k0, int zrow)
{
    const int kk   = k0 + blockIdx.y;
    const int lane = threadIdx.x & 63;
    const int wid  = threadIdx.x >> 6;
    const int g = lane >> 4, cl = lane & 15;

    const frag_ab wa0 = *(const frag_ab*)(wfrag + ((size_t)(kk * 4 + 0) * 64 + lane) * 8);
    const frag_ab wa1 = *(const frag_ab*)(wfrag + ((size_t)(kk * 4 + 1) * 64 + lane) * 8);
    const frag_ab wa2 = *(const frag_ab*)(wfrag + ((size_t)(kk * 4 + 2) * 64 + lane) * 8);
    const frag_ab wa3 = *(const frag_ab*)(wfrag + ((size_t)(kk * 4 + 3) * 64 + lane) * 8);
    const frag_cd zf = {0.f, 0.f, 0.f, 0.f};

    const size_t gk = (size_t)kk * n_in;           // rulebook base (global k)
    const size_t ck = (size_t)blockIdx.y * n_in;   // contrib base (segment-local)

    const int t = blockIdx.x * 4 + wid;            // one 16-record tile per wave
    const int idx = t * 16 + cl;
    const bool valid = idx < n_in;

    int row = zrow;
    if (valid) row = bwd[in_idx[gk + idx]];        // fused feats[bwd] gather

    // B-operand: feats row (16B vector load, lane-parallel)
    frag_ab b = *(const frag_ab*)(featsbf + (size_t)row * C_IN + g * 8);
    frag_cd d0 = __builtin_amdgcn_mfma_f32_16x16x32_bf16(wa0, b, zf, 0, 0, 0);
    frag_cd d1 = __builtin_amdgcn_mfma_f32_16x16x32_bf16(wa1, b, zf, 0, 0, 0);
    frag_cd d2 = __builtin_amdgcn_mfma_f32_16x16x32_bf16(wa2, b, zf, 0, 0, 0);
    frag_cd d3 = __builtin_amdgcn_mfma_f32_16x16x32_bf16(wa3, b, zf, 0, 0, 0);

    if (valid) {
        // record-order row: stores from the whole wave cover a contiguous 2KB
        unsigned short* cp = contrib + (ck + idx) * C_OUT + g * 4;
        uint2 v0 = {pack2(d0[0], d0[1]), pack2(d0[2], d0[3])};
        uint2 v1 = {pack2(d1[0], d1[1]), pack2(d1[2], d1[3])};
        uint2 v2 = {pack2(d2[0], d2[1]), pack2(d2[2], d2[3])};
        uint2 v3 = {pack2(d3[0], d3[1]), pack2(d3[2], d3[3])};
        *(uint2*)(cp +  0) = v0;   // channels nb*16 + g*4 .. +3
        *(uint2*)(cp + 16) = v1;
        *(uint2*)(cp + 32) = v2;
        *(uint2*)(cp + 48) = v3;
    }
}

// ===========================================================================
// Phase B: 8 threads per output row (thread = 8 channels, 16B loads).
// Gathers contrib rows via ridx; 8 threads together fetch one 128B row.
// ===========================================================================
__global__ __launch_bounds__(256) void sic_reduce2(
    const uint4* __restrict__ contrib4,  // row r at contrib4[r*8 + ch8]
    const int* __restrict__ ridx,
    const int* __restrict__ startv, const int* __restrict__ count,
    const float* __restrict__ bias, float* __restrict__ out,
    int n_out, int first)
{
    int t = blockIdx.x * 256 + threadIdx.x;
    int dst = t >> 3, ch8 = t & 7;
    if (dst >= n_out) return;
    int s = startv[dst], c = count[dst];

    size_t ob = (size_t)dst * C_OUT + ch8 * 8;
    float4 a0, a1;
    if (first) {
        a0 = *(const float4*)(bias + ch8 * 8);
        a1 = *(const float4*)(bias + ch8 * 8 + 4);
    } else {
        a0 = *(const float4*)(out + ob);
        a1 = *(const float4*)(out + ob + 4);
    }
    for (int j = 0; j < c; ++j) {
        int rid = ridx[s + j];
        uint4 v = contrib4[(size_t)rid * 8 + ch8];
        a0.x += bflo(v.x); a0.y += bfhi(v.x);
        a0.z += bflo(v.y); a0.w += bfhi(v.y);
        a1.x += bflo(v.z); a1.y += bfhi(v.z);
        a1.z += bflo(v.w); a1.w += bfhi(v.w);
    }
    *(float4*)(out + ob)     = a0;
    *(float4*)(out + ob + 4) = a1;
}

// ===========================================================================
extern "C" void kernel_launch(void* const* d_in, const int* in_sizes, int n_in_cnt,
                              void* d_out, int out_size, void* d_ws, size_t ws_size,
                              hipStream_t stream) {
    const float* feats   = (const float*)d_in[0];
    const float* weight  = (const float*)d_in[1];
    const float* bias    = (const float*)d_in[2];
    const int*   bwd     = (const int*)d_in[3];
    const int*   in_idx  = (const int*)d_in[4];
    const int*   out_idx = (const int*)d_in[5];
    float*       out     = (float*)d_out;

    const int n_in  = in_sizes[0] / C_IN;      // 100000
    const int n_out = out_size / C_OUT;        // 800000
    const size_t P  = (size_t)KK * n_in;       // 2.7M records

    const int NCH1 = (n_out + 511) / 512;      // 1563
    const int NCH2 = (NCH1 + 511) / 512;       // 4

    // ---- workspace layout (int units) ----
    const size_t NOUTr   = ((size_t)n_out + 255) & ~(size_t)255;
    const size_t o_cnt   = 0;
    const size_t o_stv   = NOUTr;
    const size_t o_cur   = 2 * NOUTr;
    const size_t o_s1    = 3 * NOUTr;                 // sums1 (NCH1)
    const size_t S1r     = ((size_t)NCH1 + 255) & ~(size_t)255;
    const size_t o_s1e   = o_s1 + S1r;                // sums1e (NCH1)
    const size_t o_s2    = o_s1e + S1r;               // sums2 (512)
    const size_t o_rix   = o_s2 + 512;                // ridx (P)
    const size_t o_fbf   = (o_rix + P + 255) & ~(size_t)255;
    const size_t fbf_i   = ((size_t)(n_in + 16) * C_IN * 2 + 3) / 4;
    const size_t o_wfr   = (o_fbf + fbf_i + 255) & ~(size_t)255;
    const size_t wfr_i   = (size_t)KK * 4 * 64 * 8 * 2 / 4;
    const size_t o_ctr   = ((o_wfr + wfr_i + 255) & ~(size_t)255);
    // align contrib to 16B (int offset multiple of 4: already 256-aligned)

    const size_t ws_ints = ws_size / 4;
    // records that fit in the remaining workspace (64 shorts = 32 ints each)
    size_t cap_recs = (ws_ints > o_ctr) ? (ws_ints - o_ctr) / 32 : 0;
    int kseg_max = (int)(cap_recs / (size_t)n_in);
    if (kseg_max > KK) kseg_max = KK;

    if (kseg_max < 1 || NCH2 > 512) {
        // fallback: round-1 atomic path
        const int total4 = out_size / 4;
        hipLaunchKernelGGL(sic_init_bias, dim3(2048), dim3(256), 0, stream,
                           (float4*)out, (const float4*)bias, total4);
        hipLaunchKernelGGL(sic_scatter, dim3(160, KK), dim3(256), 0, stream,
                           feats, weight, bwd, in_idx, out_idx, out, n_in);
        return;
    }

    int* ws = (int*)d_ws;
    int* count  = ws + o_cnt;
    int* startv = ws + o_stv;
    int* cursor = ws + o_cur;
    int* sums1  = ws + o_s1;
    int* sums1e = ws + o_s1e;
    int* sums2  = ws + o_s2;
    int* ridx   = ws + o_rix;
    short* featsbf = (short*)(ws + o_fbf);
    short* wfrag   = (short*)(ws + o_wfr);
    unsigned short* contrib = (unsigned short*)(ws + o_ctr);

    // one-time conversions
    hipLaunchKernelGGL(sic_fconv, dim3(((n_in + 1) * 4 + 255) / 256), dim3(256), 0, stream,
                       feats, featsbf, n_in);
    hipLaunchKernelGGL(sic_wconv, dim3((KK * 4 * 64 + 255) / 256), dim3(256), 0, stream,
                       weight, wfrag);

    const int ntiles = (n_in + 15) / 16;
    const int gx_gemm = (ntiles + 3) / 4;      // one tile per wave

    // segment loop over k (single pass when contrib fits: kseg_max == 27)
    for (int k0 = 0; k0 < KK; k0 += kseg_max) {
        const int kseg = (KK - k0 < kseg_max) ? (KK - k0) : kseg_max;
        const int pseg = kseg * n_in;
        const int gp   = (pseg + 255) / 256;
        const int* oseg = out_idx + (size_t)k0 * n_in;

        hipLaunchKernelGGL(sic_zero, dim3(1024), dim3(512), 0, stream, count, n_out);
        hipLaunchKernelGGL(sic_hist2, dim3(gp), dim3(256), 0, stream, oseg, count, pseg);
        hipLaunchKernelGGL(sic_scan_chunk, dim3(NCH1), dim3(512), 0, stream,
                           count, startv, sums1, n_out);
        hipLaunchKernelGGL(sic_scan_chunk, dim3(NCH2), dim3(512), 0, stream,
                           sums1, sums1e, sums2, NCH1);
        hipLaunchKernelGGL(sic_scan_small, dim3(1), dim3(512), 0, stream, sums2, NCH2);
        hipLaunchKernelGGL(sic_scan_addback, dim3(NCH2), dim3(512), 0, stream,
                           sums1e, sums2, NCH1);
        hipLaunchKernelGGL(sic_scan_addback_cur, dim3(NCH1), dim3(512), 0, stream,
                           startv, cursor, sums1e, n_out);
        hipLaunchKernelGGL(sic_fill2, dim3(gp), dim3(256), 0, stream,
                           oseg, cursor, ridx, pseg);
        hipLaunchKernelGGL(sic_gemm, dim3(gx_gemm, kseg), dim3(256), 0, stream,
                           in_idx, bwd, featsbf, wfrag, contrib, n_in, k0, n_in);
        // 8 threads per output row
        hipLaunchKernelGGL(sic_reduce2, dim3((n_out * 8 + 255) / 256), dim3(256), 0, stream,
                           (const uint4*)contrib, ridx, startv, count, bias, out,
                           n_out, (k0 == 0) ? 1 : 0);
    }
}

// Round 7
// 438.902 us; speedup vs baseline: 3.5676x; 1.5745x over previous
//
#include <hip/hip_runtime.h>

#define C_IN  32
#define C_OUT 64
#define KK    27

using frag_ab = __attribute__((ext_vector_type(8))) short;  // 8 bf16
using frag_cd = __attribute__((ext_vector_type(4))) float;  // 4 fp32

static __device__ inline unsigned short f2bf(float f) {   // RTNE f32->bf16
    unsigned u = __float_as_uint(f);
    return (unsigned short)((u + 0x7fffu + ((u >> 16) & 1u)) >> 16);
}
static __device__ inline unsigned pack2(float a, float b) {
    return (unsigned)f2bf(a) | ((unsigned)f2bf(b) << 16);
}
static __device__ inline float bflo(unsigned u) { return __uint_as_float(u << 16); }
static __device__ inline float bfhi(unsigned u) { return __uint_as_float(u & 0xffff0000u); }

// ===========================================================================
// Fallback path (round-1, passing) if workspace too small
// ===========================================================================
__global__ __launch_bounds__(256) void sic_init_bias(float4* __restrict__ out4,
                                                     const float4* __restrict__ bias4,
                                                     int total4) {
    int idx = blockIdx.x * 256 + threadIdx.x, stride = gridDim.x * 256;
    for (int i = idx; i < total4; i += stride) out4[i] = bias4[i & 15];
}

__global__ __launch_bounds__(256) void sic_scatter(
    const float* __restrict__ feats, const float* __restrict__ weight,
    const int* __restrict__ bwd, const int* __restrict__ in_idx,
    const int* __restrict__ out_idx, float* __restrict__ out, int n_in)
{
    const int k = blockIdx.y, lane = threadIdx.x & 63, wid = threadIdx.x >> 6;
    float w[C_IN];
    const float* wk = weight + k * (C_IN * C_OUT);
#pragma unroll
    for (int i = 0; i < C_IN; ++i) w[i] = wk[i * C_OUT + lane];
    const int waves_total = gridDim.x * 4;
    const long long base = (long long)k * n_in;
    for (int p = blockIdx.x * 4 + wid; p < n_in; p += waves_total) {
        int src = __builtin_amdgcn_readfirstlane(in_idx[base + p]);
        int dst = __builtin_amdgcn_readfirstlane(out_idx[base + p]);
        int row = __builtin_amdgcn_readfirstlane(bwd[src]);
        const float* f = feats + (long long)row * C_IN;
        float acc = 0.0f;
#pragma unroll
        for (int i = 0; i < C_IN; ++i) acc = fmaf(f[i], w[i], acc);
        atomicAdd(out + (long long)dst * C_OUT + lane, acc);
    }
}

// ===========================================================================
// Prep kernels
// ===========================================================================
__global__ __launch_bounds__(512) void sic_zero(int* __restrict__ p, int n) {
    int i = blockIdx.x * 512 + threadIdx.x, stride = gridDim.x * 512;
    for (; i < n; i += stride) p[i] = 0;
}

// feats (f32) -> featsbf (bf16), plus one zeroed pad row at index n_in
__global__ __launch_bounds__(256) void sic_fconv(const float* __restrict__ feats,
                                                 short* __restrict__ featsbf, int n_in) {
    int t = blockIdx.x * 256 + threadIdx.x;
    if (t >= (n_in + 1) * 4) return;
    int row = t >> 2, c8 = (t & 3) * 8;
    uint4 v = {0u, 0u, 0u, 0u};
    if (row < n_in) {
        const float* fp = feats + (size_t)row * C_IN + c8;
        float4 f0 = ((const float4*)fp)[0];
        float4 f1 = ((const float4*)fp)[1];
        v.x = pack2(f0.x, f0.y);
        v.y = pack2(f0.z, f0.w);
        v.z = pack2(f1.x, f1.y);
        v.w = pack2(f1.z, f1.w);
    }
    ((uint4*)featsbf)[t] = v;
}

// weight (f32 [27][32][64]) -> bf16 fragments [27][4][64 lanes][8]
// lane l (g=l>>4, cl=l&15), block nb: elems W[k][g*8+j][nb*16+cl]
__global__ __launch_bounds__(256) void sic_wconv(const float* __restrict__ weight,
                                                 short* __restrict__ wfrag) {
    int t = blockIdx.x * 256 + threadIdx.x;
    if (t >= KK * 4 * 64) return;
    int l = t & 63, nb = (t >> 6) & 3, k = t >> 8;
    int g = l >> 4, cl = l & 15;
    const float* wp = weight + (size_t)k * (C_IN * C_OUT) + nb * 16 + cl;
    float r[8];
#pragma unroll
    for (int j = 0; j < 8; ++j) r[j] = wp[(size_t)(g * 8 + j) * C_OUT];
    uint4 v = {pack2(r[0], r[1]), pack2(r[2], r[3]), pack2(r[4], r[5]), pack2(r[6], r[7])};
    ((uint4*)wfrag)[t] = v;
}

// histogram by destination row (segment of the rulebook)
__global__ __launch_bounds__(256) void sic_hist2(const int* __restrict__ out_idx_seg,
                                                 int* __restrict__ count, int pseg) {
    int i = blockIdx.x * 256 + threadIdx.x;
    if (i < pseg) atomicAdd(&count[out_idx_seg[i]], 1);
}

// ---- 2-level exclusive scan machinery ----
__global__ __launch_bounds__(512) void sic_scan_chunk(const int* __restrict__ in,
                                                      int* __restrict__ outExcl,
                                                      int* __restrict__ sums, int n) {
    __shared__ int sm[512];
    int tid = threadIdx.x, g = blockIdx.x * 512 + tid;
    int e = (g < n) ? in[g] : 0;
    sm[tid] = e;
    __syncthreads();
    for (int off = 1; off < 512; off <<= 1) {
        int t = (tid >= off) ? sm[tid - off] : 0;
        __syncthreads();
        sm[tid] += t;
        __syncthreads();
    }
    if (g < n) outExcl[g] = sm[tid] - e;
    if (tid == 511) sums[blockIdx.x] = sm[511];
}

__global__ __launch_bounds__(512) void sic_scan_small(int* __restrict__ buf, int n) {
    __shared__ int sm[512];
    int tid = threadIdx.x;
    int e = (tid < n) ? buf[tid] : 0;
    sm[tid] = e;
    __syncthreads();
    for (int off = 1; off < 512; off <<= 1) {
        int t = (tid >= off) ? sm[tid - off] : 0;
        __syncthreads();
        sm[tid] += t;
        __syncthreads();
    }
    if (tid < n) buf[tid] = sm[tid] - e;
}

__global__ __launch_bounds__(512) void sic_scan_addback(int* __restrict__ arr,
                                                        const int* __restrict__ sums, int n) {
    int g = blockIdx.x * 512 + threadIdx.x;
    if (g < n) arr[g] += sums[blockIdx.x];
}

__global__ __launch_bounds__(512) void sic_scan_addback_cur(int* __restrict__ startv,
                                                            int* __restrict__ cursor,
                                                            const int* __restrict__ sums, int n) {
    int g = blockIdx.x * 512 + threadIdx.x;
    if (g < n) {
        int v = startv[g] + sums[blockIdx.x];
        startv[g] = v;
        cursor[g] = v;
    }
}

// ===========================================================================
// Phase A (merged): per-k MFMA; wave claims dst-sorted slots via atomic
// cursor, transposes its 16x64 tile through LDS, stores each record as ONE
// contiguous 128B row at contrib[pos]. No fill kernel, no ridx.
// Lane (g,cl) reg j of D_nb = channel nb*16+g*4+j of record cl (verified).
// ===========================================================================
__global__ __launch_bounds__(256) void sic_gemm2(
    const int* __restrict__ in_idx,     // global rulebook [KK][n_in]
    const int* __restrict__ out_idx,
    const int* __restrict__ bwd,
    const short* __restrict__ featsbf,  // [(n_in+pad)][32] bf16
    const short* __restrict__ wfrag,    // [KK][4][64][8] bf16
    int* __restrict__ cursor,           // per-dst slot cursor (pre-set to startv)
    unsigned short* __restrict__ contrib,
    int n_in, int k0, int zrow)
{
    __shared__ unsigned smU[4][16][40];   // [wave][record][32 uints + pad8]
    const int kk   = k0 + blockIdx.y;
    const int lane = threadIdx.x & 63;
    const int wid  = threadIdx.x >> 6;
    const int g = lane >> 4, cl = lane & 15;

    const frag_ab wa0 = *(const frag_ab*)(wfrag + ((size_t)(kk * 4 + 0) * 64 + lane) * 8);
    const frag_ab wa1 = *(const frag_ab*)(wfrag + ((size_t)(kk * 4 + 1) * 64 + lane) * 8);
    const frag_ab wa2 = *(const frag_ab*)(wfrag + ((size_t)(kk * 4 + 2) * 64 + lane) * 8);
    const frag_ab wa3 = *(const frag_ab*)(wfrag + ((size_t)(kk * 4 + 3) * 64 + lane) * 8);
    const frag_cd zf = {0.f, 0.f, 0.f, 0.f};

    const size_t gk  = (size_t)kk * n_in;
    const int t      = blockIdx.x * 4 + wid;   // one 16-record tile per wave
    const int tbase  = t * 16;
    const int idx    = tbase + cl;
    const bool valid = idx < n_in;

    int row = zrow, dst = 0;
    if (valid) {
        row = bwd[in_idx[gk + idx]];           // fused feats[bwd] gather
        dst = out_idx[gk + idx];
    }
    // slot claim: one lane per record (g==0)
    int pos = 0;
    if (g == 0 && valid) pos = atomicAdd(&cursor[dst], 1);

    frag_ab b = *(const frag_ab*)(featsbf + (size_t)row * C_IN + g * 8);
    frag_cd d0 = __builtin_amdgcn_mfma_f32_16x16x32_bf16(wa0, b, zf, 0, 0, 0);
    frag_cd d1 = __builtin_amdgcn_mfma_f32_16x16x32_bf16(wa1, b, zf, 0, 0, 0);
    frag_cd d2 = __builtin_amdgcn_mfma_f32_16x16x32_bf16(wa2, b, zf, 0, 0, 0);
    frag_cd d3 = __builtin_amdgcn_mfma_f32_16x16x32_bf16(wa3, b, zf, 0, 0, 0);

    // transpose through LDS: record-major rows of 32 uints (64 bf16 ch)
    smU[wid][cl][0  + g * 2 + 0] = pack2(d0[0], d0[1]);
    smU[wid][cl][0  + g * 2 + 1] = pack2(d0[2], d0[3]);
    smU[wid][cl][8  + g * 2 + 0] = pack2(d1[0], d1[1]);
    smU[wid][cl][8  + g * 2 + 1] = pack2(d1[2], d1[3]);
    smU[wid][cl][16 + g * 2 + 0] = pack2(d2[0], d2[1]);
    smU[wid][cl][16 + g * 2 + 1] = pack2(d2[2], d2[3]);
    smU[wid][cl][24 + g * 2 + 0] = pack2(d3[0], d3[1]);
    smU[wid][cl][24 + g * 2 + 1] = pack2(d3[2], d3[3]);
    __syncthreads();

    // write-out: 8 lanes per record, each lane one 16B chunk -> 128B/row
#pragma unroll
    for (int p = 0; p < 2; ++p) {
        int r = (lane >> 3) + p * 8;          // record 0..15
        int c = lane & 7;                     // 16B chunk 0..7
        uint4 v = {smU[wid][r][c * 4 + 0], smU[wid][r][c * 4 + 1],
                   smU[wid][r][c * 4 + 2], smU[wid][r][c * 4 + 3]};
        int pos_r = __shfl(pos, r, 64);       // pos lives at lane r (g==0,cl==r)
        if (tbase + r < n_in) {
            *(uint4*)(contrib + (size_t)pos_r * C_OUT + c * 8) = v;
        }
    }
}

// ===========================================================================
// Phase B: fully streaming reduce. Slots for a dst are contiguous;
// 8 threads per dst, each 16B per contributor row; coalesced out-write.
// ===========================================================================
__global__ __launch_bounds__(256) void sic_reduce3(
    const uint4* __restrict__ contrib4,   // row r at contrib4[r*8 + chunk]
    const int* __restrict__ startv, const int* __restrict__ count,
    const float* __restrict__ bias, float* __restrict__ out,
    int n_out, int first)
{
    int t = blockIdx.x * 256 + threadIdx.x;
    int dst = t >> 3, c8 = t & 7;
    if (dst >= n_out) return;
    int s = startv[dst], c = count[dst];

    size_t ob = (size_t)dst * C_OUT + c8 * 8;
    float4 a0, a1;
    if (first) {
        a0 = *(const float4*)(bias + c8 * 8);
        a1 = *(const float4*)(bias + c8 * 8 + 4);
    } else {
        a0 = *(const float4*)(out + ob);
        a1 = *(const float4*)(out + ob + 4);
    }
    const uint4* p = contrib4 + (size_t)s * 8 + c8;
    for (int j = 0; j < c; ++j) {
        uint4 v = p[(size_t)j * 8];           // contiguous rows: streaming
        a0.x += bflo(v.x); a0.y += bfhi(v.x);
        a0.z += bflo(v.y); a0.w += bfhi(v.y);
        a1.x += bflo(v.z); a1.y += bfhi(v.z);
        a1.z += bflo(v.w); a1.w += bfhi(v.w);
    }
    *(float4*)(out + ob)     = a0;
    *(float4*)(out + ob + 4) = a1;
}

// ===========================================================================
extern "C" void kernel_launch(void* const* d_in, const int* in_sizes, int n_in_cnt,
                              void* d_out, int out_size, void* d_ws, size_t ws_size,
                              hipStream_t stream) {
    const float* feats   = (const float*)d_in[0];
    const float* weight  = (const float*)d_in[1];
    const float* bias    = (const float*)d_in[2];
    const int*   bwd     = (const int*)d_in[3];
    const int*   in_idx  = (const int*)d_in[4];
    const int*   out_idx = (const int*)d_in[5];
    float*       out     = (float*)d_out;

    const int n_in  = in_sizes[0] / C_IN;      // 100000
    const int n_out = out_size / C_OUT;        // 800000
    const size_t P  = (size_t)KK * n_in;       // 2.7M records

    const int NCH1 = (n_out + 511) / 512;      // 1563
    const int NCH2 = (NCH1 + 511) / 512;       // 4

    // ---- workspace layout (int units) ----
    const size_t NOUTr   = ((size_t)n_out + 255) & ~(size_t)255;
    const size_t o_cnt   = 0;
    const size_t o_stv   = NOUTr;
    const size_t o_cur   = 2 * NOUTr;
    const size_t o_s1    = 3 * NOUTr;
    const size_t S1r     = ((size_t)NCH1 + 255) & ~(size_t)255;
    const size_t o_s1e   = o_s1 + S1r;
    const size_t o_s2    = o_s1e + S1r;
    const size_t o_fbf   = (o_s2 + 512 + 255) & ~(size_t)255;
    const size_t fbf_i   = ((size_t)(n_in + 16) * C_IN * 2 + 3) / 4;
    const size_t o_wfr   = (o_fbf + fbf_i + 255) & ~(size_t)255;
    const size_t wfr_i   = (size_t)KK * 4 * 64 * 8 * 2 / 4;
    const size_t o_ctr   = (o_wfr + wfr_i + 255) & ~(size_t)255;   // contrib

    const size_t ws_ints = ws_size / 4;
    size_t cap_recs = (ws_ints > o_ctr) ? (ws_ints - o_ctr) / 32 : 0;  // 128B/rec
    int kseg_max = (int)(cap_recs / (size_t)n_in);
    if (kseg_max > KK) kseg_max = KK;

    if (kseg_max < 1 || NCH2 > 512) {
        // fallback: round-1 atomic path
        const int total4 = out_size / 4;
        hipLaunchKernelGGL(sic_init_bias, dim3(2048), dim3(256), 0, stream,
                           (float4*)out, (const float4*)bias, total4);
        hipLaunchKernelGGL(sic_scatter, dim3(160, KK), dim3(256), 0, stream,
                           feats, weight, bwd, in_idx, out_idx, out, n_in);
        return;
    }

    int* ws = (int*)d_ws;
    int* count  = ws + o_cnt;
    int* startv = ws + o_stv;
    int* cursor = ws + o_cur;
    int* sums1  = ws + o_s1;
    int* sums1e = ws + o_s1e;
    int* sums2  = ws + o_s2;
    short* featsbf = (short*)(ws + o_fbf);
    short* wfrag   = (short*)(ws + o_wfr);
    unsigned short* contrib = (unsigned short*)(ws + o_ctr);

    // one-time conversions
    hipLaunchKernelGGL(sic_fconv, dim3(((n_in + 1) * 4 + 255) / 256), dim3(256), 0, stream,
                       feats, featsbf, n_in);
    hipLaunchKernelGGL(sic_wconv, dim3((KK * 4 * 64 + 255) / 256), dim3(256), 0, stream,
                       weight, wfrag);

    const int ntiles  = (n_in + 15) / 16;
    const int gx_gemm = (ntiles + 3) / 4;      // one tile per wave

    // segment loop over k (single pass when contrib fits: kseg_max == 27)
    for (int k0 = 0; k0 < KK; k0 += kseg_max) {
        const int kseg = (KK - k0 < kseg_max) ? (KK - k0) : kseg_max;
        const int pseg = kseg * n_in;
        const int gp   = (pseg + 255) / 256;
        const int* oseg = out_idx + (size_t)k0 * n_in;

        hipLaunchKernelGGL(sic_zero, dim3(1024), dim3(512), 0, stream, count, n_out);
        hipLaunchKernelGGL(sic_hist2, dim3(gp), dim3(256), 0, stream, oseg, count, pseg);
        hipLaunchKernelGGL(sic_scan_chunk, dim3(NCH1), dim3(512), 0, stream,
                           count, startv, sums1, n_out);
        hipLaunchKernelGGL(sic_scan_chunk, dim3(NCH2), dim3(512), 0, stream,
                           sums1, sums1e, sums2, NCH1);
        hipLaunchKernelGGL(sic_scan_small, dim3(1), dim3(512), 0, stream, sums2, NCH2);
        hipLaunchKernelGGL(sic_scan_addback, dim3(NCH2), dim3(512), 0, stream,
                           sums1e, sums2, NCH1);
        hipLaunchKernelGGL(sic_scan_addback_cur, dim3(NCH1), dim3(512), 0, stream,
                           startv, cursor, sums1e, n_out);
        // merged: MFMA + slot claim + dst-sorted 128B-row scatter
        hipLaunchKernelGGL(sic_gemm2, dim3(gx_gemm, kseg), dim3(256), 0, stream,
                           in_idx, oseg - (size_t)k0 * n_in + (size_t)k0 * n_in, // = in place
                           bwd, featsbf, wfrag, cursor, contrib, n_in, k0, n_in);
        // streaming reduce: 8 threads per output row
        hipLaunchKernelGGL(sic_reduce3, dim3((n_out * 8 + 255) / 256), dim3(256), 0, stream,
                           (const uint4*)contrib, startv, count, bias, out,
                           n_out, (k0 == 0) ? 1 : 0);
    }
}

// Round 9
// 361.970 us; speedup vs baseline: 4.3258x; 1.2125x over previous
//
#include <hip/hip_runtime.h>

#define C_IN  32
#define C_OUT 64
#define KK    27

using frag_ab = __attribute__((ext_vector_type(8))) short;  // 8 bf16
using frag_cd = __attribute__((ext_vector_type(4))) float;  // 4 fp32
using u32x4   = __attribute__((ext_vector_type(4))) unsigned int;  // nt-able

static __device__ inline unsigned short f2bf(float f) {   // RTNE f32->bf16
    unsigned u = __float_as_uint(f);
    return (unsigned short)((u + 0x7fffu + ((u >> 16) & 1u)) >> 16);
}
static __device__ inline unsigned pack2(float a, float b) {
    return (unsigned)f2bf(a) | ((unsigned)f2bf(b) << 16);
}
static __device__ inline float bflo(unsigned u) { return __uint_as_float(u << 16); }
static __device__ inline float bfhi(unsigned u) { return __uint_as_float(u & 0xffff0000u); }

// ===========================================================================
// Fallback path (round-1, passing) if workspace too small
// ===========================================================================
__global__ __launch_bounds__(256) void sic_init_bias(float4* __restrict__ out4,
                                                     const float4* __restrict__ bias4,
                                                     int total4) {
    int idx = blockIdx.x * 256 + threadIdx.x, stride = gridDim.x * 256;
    for (int i = idx; i < total4; i += stride) out4[i] = bias4[i & 15];
}

__global__ __launch_bounds__(256) void sic_scatter(
    const float* __restrict__ feats, const float* __restrict__ weight,
    const int* __restrict__ bwd, const int* __restrict__ in_idx,
    const int* __restrict__ out_idx, float* __restrict__ out, int n_in)
{
    const int k = blockIdx.y, lane = threadIdx.x & 63, wid = threadIdx.x >> 6;
    float w[C_IN];
    const float* wk = weight + k * (C_IN * C_OUT);
#pragma unroll
    for (int i = 0; i < C_IN; ++i) w[i] = wk[i * C_OUT + lane];
    const int waves_total = gridDim.x * 4;
    const long long base = (long long)k * n_in;
    for (int p = blockIdx.x * 4 + wid; p < n_in; p += waves_total) {
        int src = __builtin_amdgcn_readfirstlane(in_idx[base + p]);
        int dst = __builtin_amdgcn_readfirstlane(out_idx[base + p]);
        int row = __builtin_amdgcn_readfirstlane(bwd[src]);
        const float* f = feats + (long long)row * C_IN;
        float acc = 0.0f;
#pragma unroll
        for (int i = 0; i < C_IN; ++i) acc = fmaf(f[i], w[i], acc);
        atomicAdd(out + (long long)dst * C_OUT + lane, acc);
    }
}

// ===========================================================================
// Prep kernels
// ===========================================================================
__global__ __launch_bounds__(512) void sic_zero(int* __restrict__ p, int n) {
    int i = blockIdx.x * 512 + threadIdx.x, stride = gridDim.x * 512;
    for (; i < n; i += stride) p[i] = 0;
}

// feats (f32) -> featsbf (bf16), plus one zeroed pad row at index n_in
__global__ __launch_bounds__(256) void sic_fconv(const float* __restrict__ feats,
                                                 short* __restrict__ featsbf, int n_in) {
    int t = blockIdx.x * 256 + threadIdx.x;
    if (t >= (n_in + 1) * 4) return;
    int row = t >> 2, c8 = (t & 3) * 8;
    uint4 v = {0u, 0u, 0u, 0u};
    if (row < n_in) {
        const float* fp = feats + (size_t)row * C_IN + c8;
        float4 f0 = ((const float4*)fp)[0];
        float4 f1 = ((const float4*)fp)[1];
        v.x = pack2(f0.x, f0.y);
        v.y = pack2(f0.z, f0.w);
        v.z = pack2(f1.x, f1.y);
        v.w = pack2(f1.z, f1.w);
    }
    ((uint4*)featsbf)[t] = v;
}

// weight (f32 [27][32][64]) -> bf16 fragments [27][4][64 lanes][8]
// lane l (g=l>>4, cl=l&15), block nb: elems W[k][g*8+j][nb*16+cl]
__global__ __launch_bounds__(256) void sic_wconv(const float* __restrict__ weight,
                                                 short* __restrict__ wfrag) {
    int t = blockIdx.x * 256 + threadIdx.x;
    if (t >= KK * 4 * 64) return;
    int l = t & 63, nb = (t >> 6) & 3, k = t >> 8;
    int g = l >> 4, cl = l & 15;
    const float* wp = weight + (size_t)k * (C_IN * C_OUT) + nb * 16 + cl;
    float r[8];
#pragma unroll
    for (int j = 0; j < 8; ++j) r[j] = wp[(size_t)(g * 8 + j) * C_OUT];
    uint4 v = {pack2(r[0], r[1]), pack2(r[2], r[3]), pack2(r[4], r[5]), pack2(r[6], r[7])};
    ((uint4*)wfrag)[t] = v;
}

// histogram by destination + per-record ordinal (the atomic's return value)
__global__ __launch_bounds__(256) void sic_hist3(const int* __restrict__ out_idx_seg,
                                                 int* __restrict__ count,
                                                 int* __restrict__ ord, int pseg) {
    int i = blockIdx.x * 256 + threadIdx.x;
    if (i < pseg) {
        ord[i] = atomicAdd(&count[out_idx_seg[i]], 1);  // coalesced ord write
    }
}

// ---- 2-level exclusive scan machinery ----
__global__ __launch_bounds__(512) void sic_scan_chunk(const int* __restrict__ in,
                                                      int* __restrict__ outExcl,
                                                      int* __restrict__ sums, int n) {
    __shared__ int sm[512];
    int tid = threadIdx.x, g = blockIdx.x * 512 + tid;
    int e = (g < n) ? in[g] : 0;
    sm[tid] = e;
    __syncthreads();
    for (int off = 1; off < 512; off <<= 1) {
        int t = (tid >= off) ? sm[tid - off] : 0;
        __syncthreads();
        sm[tid] += t;
        __syncthreads();
    }
    if (g < n) outExcl[g] = sm[tid] - e;
    if (tid == 511) sums[blockIdx.x] = sm[511];
}

__global__ __launch_bounds__(512) void sic_scan_small(int* __restrict__ buf, int n) {
    __shared__ int sm[512];
    int tid = threadIdx.x;
    int e = (tid < n) ? buf[tid] : 0;
    sm[tid] = e;
    __syncthreads();
    for (int off = 1; off < 512; off <<= 1) {
        int t = (tid >= off) ? sm[tid - off] : 0;
        __syncthreads();
        sm[tid] += t;
        __syncthreads();
    }
    if (tid < n) buf[tid] = sm[tid] - e;
}

__global__ __launch_bounds__(512) void sic_scan_addback(int* __restrict__ arr,
                                                        const int* __restrict__ sums, int n) {
    int g = blockIdx.x * 512 + threadIdx.x;
    if (g < n) arr[g] += sums[blockIdx.x];
}

// ===========================================================================
// Phase A: per-k MFMA; slot = startv[dst] + ord[rec] (no atomics here).
// Transpose 16x64 tile through LDS; nt-store each record as one 128B row.
// Lane (g,cl) reg j of D_nb = channel nb*16+g*4+j of record cl (verified).
// ===========================================================================
__global__ __launch_bounds__(256) void sic_gemm3(
    const int* __restrict__ in_idx,     // global rulebook [KK][n_in]
    const int* __restrict__ out_idx,
    const int* __restrict__ bwd,
    const int* __restrict__ ord,        // segment-local [kseg*n_in]
    const int* __restrict__ startv,     // per-dst slot base
    const short* __restrict__ featsbf,  // [(n_in+pad)][32] bf16
    const short* __restrict__ wfrag,    // [KK][4][64][8] bf16
    unsigned short* __restrict__ contrib,
    int n_in, int k0, int zrow)
{
    __shared__ unsigned smU[4][16][40];   // [wave][record][32 uints + pad8]
    const int kk   = k0 + blockIdx.y;
    const int lane = threadIdx.x & 63;
    const int wid  = threadIdx.x >> 6;
    const int g = lane >> 4, cl = lane & 15;

    const frag_ab wa0 = *(const frag_ab*)(wfrag + ((size_t)(kk * 4 + 0) * 64 + lane) * 8);
    const frag_ab wa1 = *(const frag_ab*)(wfrag + ((size_t)(kk * 4 + 1) * 64 + lane) * 8);
    const frag_ab wa2 = *(const frag_ab*)(wfrag + ((size_t)(kk * 4 + 2) * 64 + lane) * 8);
    const frag_ab wa3 = *(const frag_ab*)(wfrag + ((size_t)(kk * 4 + 3) * 64 + lane) * 8);
    const frag_cd zf = {0.f, 0.f, 0.f, 0.f};

    const size_t gk  = (size_t)kk * n_in;            // rulebook base (global k)
    const size_t sk  = (size_t)blockIdx.y * n_in;    // ord base (segment-local)
    const int t      = blockIdx.x * 4 + wid;         // one 16-record tile per wave
    const int tbase  = t * 16;
    const int idx    = tbase + cl;
    const bool valid = idx < n_in;

    int row = zrow, pos = 0;
    if (valid) {
        row = bwd[in_idx[gk + idx]];                 // fused feats[bwd] gather
        int dst = out_idx[gk + idx];
        pos = startv[dst] + ord[sk + idx];           // slot, no atomics
    }

    frag_ab b = *(const frag_ab*)(featsbf + (size_t)row * C_IN + g * 8);
    frag_cd d0 = __builtin_amdgcn_mfma_f32_16x16x32_bf16(wa0, b, zf, 0, 0, 0);
    frag_cd d1 = __builtin_amdgcn_mfma_f32_16x16x32_bf16(wa1, b, zf, 0, 0, 0);
    frag_cd d2 = __builtin_amdgcn_mfma_f32_16x16x32_bf16(wa2, b, zf, 0, 0, 0);
    frag_cd d3 = __builtin_amdgcn_mfma_f32_16x16x32_bf16(wa3, b, zf, 0, 0, 0);

    // transpose through LDS: record-major rows of 32 uints (64 bf16 ch)
    smU[wid][cl][0  + g * 2 + 0] = pack2(d0[0], d0[1]);
    smU[wid][cl][0  + g * 2 + 1] = pack2(d0[2], d0[3]);
    smU[wid][cl][8  + g * 2 + 0] = pack2(d1[0], d1[1]);
    smU[wid][cl][8  + g * 2 + 1] = pack2(d1[2], d1[3]);
    smU[wid][cl][16 + g * 2 + 0] = pack2(d2[0], d2[1]);
    smU[wid][cl][16 + g * 2 + 1] = pack2(d2[2], d2[3]);
    smU[wid][cl][24 + g * 2 + 0] = pack2(d3[0], d3[1]);
    smU[wid][cl][24 + g * 2 + 1] = pack2(d3[2], d3[3]);
    __syncthreads();

    // write-out: 8 lanes per record, each lane one 16B chunk -> 128B/row
#pragma unroll
    for (int p = 0; p < 2; ++p) {
        int r = (lane >> 3) + p * 8;          // record 0..15
        int c = lane & 7;                     // 16B chunk 0..7
        u32x4 v = {smU[wid][r][c * 4 + 0], smU[wid][r][c * 4 + 1],
                   smU[wid][r][c * 4 + 2], smU[wid][r][c * 4 + 3]};
        int pos_r = __shfl(pos, r, 64);       // pos lives at any lane with cl==r
        if (tbase + r < n_in) {
            __builtin_nontemporal_store(v,
                (u32x4*)(contrib + (size_t)pos_r * C_OUT + c * 8));
        }
    }
}

// ===========================================================================
// Phase B: streaming reduce. Slots for a dst are contiguous; 8 threads/dst,
// 2-row unrolled loop of nt 16B loads; coalesced out-write with bias fused.
// ===========================================================================
__global__ __launch_bounds__(256) void sic_reduce4(
    const unsigned int* __restrict__ contribU,  // row r at contribU[r*32 ..]
    const int* __restrict__ startv, const int* __restrict__ count,
    const float* __restrict__ bias, float* __restrict__ out,
    int n_out, int first)
{
    int t = blockIdx.x * 256 + threadIdx.x;
    int dst = t >> 3, c8 = t & 7;
    if (dst >= n_out) return;
    int s = startv[dst], c = count[dst];

    size_t ob = (size_t)dst * C_OUT + c8 * 8;
    float4 a0, a1;
    if (first) {
        a0 = *(const float4*)(bias + c8 * 8);
        a1 = *(const float4*)(bias + c8 * 8 + 4);
    } else {
        a0 = *(const float4*)(out + ob);
        a1 = *(const float4*)(out + ob + 4);
    }
    const u32x4* p = (const u32x4*)(contribU + (size_t)s * 32) + c8;
    int j = 0;
    for (; j + 2 <= c; j += 2) {
        u32x4 va = __builtin_nontemporal_load(&p[(size_t)j * 8]);
        u32x4 vb = __builtin_nontemporal_load(&p[(size_t)(j + 1) * 8]);
        a0.x += bflo(va.x); a0.y += bfhi(va.x);
        a0.z += bflo(va.y); a0.w += bfhi(va.y);
        a1.x += bflo(va.z); a1.y += bfhi(va.z);
        a1.z += bflo(va.w); a1.w += bfhi(va.w);
        a0.x += bflo(vb.x); a0.y += bfhi(vb.x);
        a0.z += bflo(vb.y); a0.w += bfhi(vb.y);
        a1.x += bflo(vb.z); a1.y += bfhi(vb.z);
        a1.z += bflo(vb.w); a1.w += bfhi(vb.w);
    }
    if (j < c) {
        u32x4 va = __builtin_nontemporal_load(&p[(size_t)j * 8]);
        a0.x += bflo(va.x); a0.y += bfhi(va.x);
        a0.z += bflo(va.y); a0.w += bfhi(va.y);
        a1.x += bflo(va.z); a1.y += bfhi(va.z);
        a1.z += bflo(va.w); a1.w += bfhi(va.w);
    }
    *(float4*)(out + ob)     = a0;
    *(float4*)(out + ob + 4) = a1;
}

// ===========================================================================
extern "C" void kernel_launch(void* const* d_in, const int* in_sizes, int n_in_cnt,
                              void* d_out, int out_size, void* d_ws, size_t ws_size,
                              hipStream_t stream) {
    const float* feats   = (const float*)d_in[0];
    const float* weight  = (const float*)d_in[1];
    const float* bias    = (const float*)d_in[2];
    const int*   bwd     = (const int*)d_in[3];
    const int*   in_idx  = (const int*)d_in[4];
    const int*   out_idx = (const int*)d_in[5];
    float*       out     = (float*)d_out;

    const int n_in  = in_sizes[0] / C_IN;      // 100000
    const int n_out = out_size / C_OUT;        // 800000
    const size_t P  = (size_t)KK * n_in;       // 2.7M records

    const int NCH1 = (n_out + 511) / 512;      // 1563
    const int NCH2 = (NCH1 + 511) / 512;       // 4

    // ---- workspace layout (int units) ----
    const size_t NOUTr   = ((size_t)n_out + 255) & ~(size_t)255;
    const size_t o_cnt   = 0;
    const size_t o_stv   = NOUTr;
    const size_t o_s1    = 2 * NOUTr;
    const size_t S1r     = ((size_t)NCH1 + 255) & ~(size_t)255;
    const size_t o_s1e   = o_s1 + S1r;
    const size_t o_s2    = o_s1e + S1r;
    const size_t o_ord   = (o_s2 + 512 + 255) & ~(size_t)255;      // ord (P)
    const size_t o_fbf   = (o_ord + P + 255) & ~(size_t)255;
    const size_t fbf_i   = ((size_t)(n_in + 16) * C_IN * 2 + 3) / 4;
    const size_t o_wfr   = (o_fbf + fbf_i + 255) & ~(size_t)255;
    const size_t wfr_i   = (size_t)KK * 4 * 64 * 8 * 2 / 4;
    const size_t o_ctr   = (o_wfr + wfr_i + 255) & ~(size_t)255;   // contrib

    const size_t ws_ints = ws_size / 4;
    size_t cap_recs = (ws_ints > o_ctr) ? (ws_ints - o_ctr) / 32 : 0;  // 128B/rec
    int kseg_max = (int)(cap_recs / (size_t)n_in);
    if (kseg_max > KK) kseg_max = KK;

    if (kseg_max < 1 || NCH2 > 512) {
        // fallback: round-1 atomic path
        const int total4 = out_size / 4;
        hipLaunchKernelGGL(sic_init_bias, dim3(2048), dim3(256), 0, stream,
                           (float4*)out, (const float4*)bias, total4);
        hipLaunchKernelGGL(sic_scatter, dim3(160, KK), dim3(256), 0, stream,
                           feats, weight, bwd, in_idx, out_idx, out, n_in);
        return;
    }

    int* ws = (int*)d_ws;
    int* count  = ws + o_cnt;
    int* startv = ws + o_stv;
    int* sums1  = ws + o_s1;
    int* sums1e = ws + o_s1e;
    int* sums2  = ws + o_s2;
    int* ord    = ws + o_ord;
    short* featsbf = (short*)(ws + o_fbf);
    short* wfrag   = (short*)(ws + o_wfr);
    unsigned short* contrib = (unsigned short*)(ws + o_ctr);

    // one-time conversions
    hipLaunchKernelGGL(sic_fconv, dim3(((n_in + 1) * 4 + 255) / 256), dim3(256), 0, stream,
                       feats, featsbf, n_in);
    hipLaunchKernelGGL(sic_wconv, dim3((KK * 4 * 64 + 255) / 256), dim3(256), 0, stream,
                       weight, wfrag);

    const int ntiles  = (n_in + 15) / 16;
    const int gx_gemm = (ntiles + 3) / 4;      // one tile per wave

    // segment loop over k (single pass when contrib fits: kseg_max == 27)
    for (int k0 = 0; k0 < KK; k0 += kseg_max) {
        const int kseg = (KK - k0 < kseg_max) ? (KK - k0) : kseg_max;
        const int pseg = kseg * n_in;
        const int gp   = (pseg + 255) / 256;
        const int* oseg = out_idx + (size_t)k0 * n_in;

        hipLaunchKernelGGL(sic_zero, dim3(1024), dim3(512), 0, stream, count, n_out);
        // histogram + ordinal capture (coalesced ord write)
        hipLaunchKernelGGL(sic_hist3, dim3(gp), dim3(256), 0, stream,
                           oseg, count, ord, pseg);
        hipLaunchKernelGGL(sic_scan_chunk, dim3(NCH1), dim3(512), 0, stream,
                           count, startv, sums1, n_out);
        hipLaunchKernelGGL(sic_scan_chunk, dim3(NCH2), dim3(512), 0, stream,
                           sums1, sums1e, sums2, NCH1);
        hipLaunchKernelGGL(sic_scan_small, dim3(1), dim3(512), 0, stream, sums2, NCH2);
        hipLaunchKernelGGL(sic_scan_addback, dim3(NCH2), dim3(512), 0, stream,
                           sums1e, sums2, NCH1);
        hipLaunchKernelGGL(sic_scan_addback, dim3(NCH1), dim3(512), 0, stream,
                           startv, sums1e, n_out);
        // MFMA + dst-sorted 128B-row scatter (atomic-free)
        hipLaunchKernelGGL(sic_gemm3, dim3(gx_gemm, kseg), dim3(256), 0, stream,
                           in_idx, out_idx, bwd, ord, startv,
                           featsbf, wfrag, contrib, n_in, k0, n_in);
        // streaming reduce: 8 threads per output row
        hipLaunchKernelGGL(sic_reduce4, dim3((n_out * 8 + 255) / 256), dim3(256), 0, stream,
                           (const unsigned int*)contrib, startv, count, bias, out,
                           n_out, (k0 == 0) ? 1 : 0);
    }
}